// Round 1
// baseline (517.795 us; speedup 1.0000x reference)
//
#include <hip/hip_runtime.h>

#define EPS   0.01f
#define ALPHA 0.1f
#define H     60

__device__ __forceinline__ float softplusf(float x) {
    // stable: max(x,0) + log1p(exp(-|x|))
    float e = __expf(-fabsf(x));
    return fmaxf(x, 0.f) + __logf(1.f + e);
}

// ---- g0 = icnn(0): row-independent constant, one thread ----
__global__ void g0_kernel(const float* __restrict__ W2, const float* __restrict__ b1,
                          const float* __restrict__ b2, const float* __restrict__ W3,
                          const float* __restrict__ b3, float* __restrict__ g0_out) {
    if (threadIdx.x != 0 || blockIdx.x != 0) return;
    float h1[H];
    for (int k = 0; k < H; ++k) h1[k] = softplusf(b1[k]);
    float z3 = b3[0];
    for (int j = 0; j < H; ++j) {
        float acc = b2[j];
        for (int k = 0; k < H; ++k) acc = fmaf(W2[j * H + k], h1[k], acc);
        z3 = fmaf(W3[j], softplusf(acc), z3);
    }
    g0_out[0] = softplusf(z3);
}

// ---- main: one row per thread, fused forward + analytic backward ----
__global__ __launch_bounds__(256) void sdnn_kernel(
    const float* __restrict__ X,   const float* __restrict__ Wf,
    const float* __restrict__ W1,  const float* __restrict__ b1,
    const float* __restrict__ W2,  const float* __restrict__ b2,
    const float* __restrict__ W3,  const float* __restrict__ b3,
    const float* __restrict__ Wim2,const float* __restrict__ Wim3,
    const float* __restrict__ g0p, float* __restrict__ out, int B)
{
    __shared__ float lW2[H * H];
    __shared__ float lW1[2 * H];
    __shared__ float lb1[H];
    __shared__ float lb2[H];
    __shared__ float lW3[H];
    __shared__ float lWim2[2 * H];

    const int tid = threadIdx.x;
    for (int i = tid; i < H * H; i += 256) lW2[i] = W2[i];
    for (int i = tid; i < 2 * H; i += 256) { lW1[i] = W1[i]; lWim2[i] = Wim2[i]; }
    for (int i = tid; i < H;     i += 256) { lb1[i] = b1[i]; lb2[i] = b2[i]; lW3[i] = W3[i]; }
    __syncthreads();

    const int row = blockIdx.x * 256 + tid;
    if (row >= B) return;

    const float2 xv = ((const float2*)X)[row];
    const float x0 = xv.x, x1 = xv.y;

    // layer 1: h1 = sp(W1 x + b1)    (W1 row-major [60,2])
    float h1v[H];
#pragma unroll
    for (int k = 0; k < H; ++k)
        h1v[k] = softplusf(fmaf(lW1[2 * k], x0, fmaf(lW1[2 * k + 1], x1, lb1[k])));

    // G[k] accumulates sum_j W2[j][k] * t[j]   (t[j] = W3[j]*sigmoid(z2[j]))
    float G[H];
#pragma unroll
    for (int k = 0; k < H; ++k) G[k] = 0.f;

    const float wi30 = Wim3[0], wi31 = Wim3[1];
    float z3 = fmaf(wi30, x0, fmaf(wi31, x1, b3[0]));
    float gim0 = 0.f, gim1 = 0.f;   // sum_j t[j]*Wim2[j,:]

    for (int j = 0; j < H; ++j) {
        const float* __restrict__ wrow = &lW2[j * H];
        // z2_j = W2[j,:]·h1 + b2_j + Wim2[j,:]·x  (4 partial accs break dep chain)
        float a0 = 0.f, a1 = 0.f, a2 = 0.f, a3 = 0.f;
#pragma unroll
        for (int k = 0; k < H; k += 4) {
            a0 = fmaf(wrow[k + 0], h1v[k + 0], a0);
            a1 = fmaf(wrow[k + 1], h1v[k + 1], a1);
            a2 = fmaf(wrow[k + 2], h1v[k + 2], a2);
            a3 = fmaf(wrow[k + 3], h1v[k + 3], a3);
        }
        float acc = ((a0 + a1) + (a2 + a3))
                  + fmaf(lWim2[2 * j], x0, fmaf(lWim2[2 * j + 1], x1, lb2[j]));
        const float h2  = softplusf(acc);
        const float w3j = lW3[j];
        z3 = fmaf(w3j, h2, z3);
        const float tj = w3j * (1.f - __expf(-h2));   // W3[j]*sigmoid(z2_j)
        gim0 = fmaf(tj, lWim2[2 * j],     gim0);
        gim1 = fmaf(tj, lWim2[2 * j + 1], gim1);
#pragma unroll
        for (int k = 0; k < H; ++k) G[k] = fmaf(wrow[k], tj, G[k]);
    }

    const float g0 = g0p[0];
    const float g  = softplusf(z3);
    const float s3 = 1.f - __expf(-g);        // sigmoid(z3)
    const float u3 = (g > g0) ? s3 : 0.f;     // relu'(g-g0) * sigmoid(z3)

    // q = sum_k G[k]*sigmoid(z1_k)*W1[k,:]
    float q0 = 0.f, q1 = 0.f;
#pragma unroll
    for (int k = 0; k < H; ++k) {
        const float u1 = G[k] * (1.f - __expf(-h1v[k]));
        q0 = fmaf(u1, lW1[2 * k],     q0);
        q1 = fmaf(u1, lW1[2 * k + 1], q1);
    }
    const float dV0 = fmaf(2.f * EPS, x0, u3 * (wi30 + gim0 + q0));
    const float dV1 = fmaf(2.f * EPS, x1, u3 * (wi31 + gim1 + q1));

    const float V  = fmaxf(g - g0, 0.f) + EPS * fmaf(x0, x0, x1 * x1);
    const float f0 = fmaf(Wf[0], x0, Wf[1] * x1);
    const float f1 = fmaf(Wf[2], x0, Wf[3] * x1);
    const float stab = fmaf(ALPHA, V, fmaf(dV0, f0, dV1 * f1));
    const float r    = fmaxf(stab, 0.f);
    const float n2   = fmaf(dV0, dV0, dV1 * dV1);
    const float s    = __fdividef(r, n2);

    float2 o;
    o.x = f0 - dV0 * s;
    o.y = f1 - dV1 * s;
    ((float2*)out)[row] = o;
}

extern "C" void kernel_launch(void* const* d_in, const int* in_sizes, int n_in,
                              void* d_out, int out_size, void* d_ws, size_t ws_size,
                              hipStream_t stream) {
    const float* X    = (const float*)d_in[0];
    const float* Wf   = (const float*)d_in[1];
    const float* W1   = (const float*)d_in[2];
    const float* b1   = (const float*)d_in[3];
    const float* W2   = (const float*)d_in[4];
    const float* b2   = (const float*)d_in[5];
    const float* W3   = (const float*)d_in[6];
    const float* b3   = (const float*)d_in[7];
    const float* Wim2 = (const float*)d_in[8];
    const float* Wim3 = (const float*)d_in[9];
    float* out   = (float*)d_out;
    float* g0buf = (float*)d_ws;

    const int B = in_sizes[0] / 2;

    hipLaunchKernelGGL(g0_kernel, dim3(1), dim3(64), 0, stream,
                       W2, b1, b2, W3, b3, g0buf);
    hipLaunchKernelGGL(sdnn_kernel, dim3((B + 255) / 256), dim3(256), 0, stream,
                       X, Wf, W1, b1, W2, b2, W3, b3, Wim2, Wim3, g0buf, out, B);
}

// Round 2
// 307.056 us; speedup vs baseline: 1.6863x; 1.6863x over previous
//
#include <hip/hip_runtime.h>

#define EPS   0.01f
#define ALPHA 0.1f
#define H     60

__device__ __forceinline__ float softplusf(float x) {
    // stable: max(x,0) + log1p(exp(-|x|))
    float e = __expf(-fabsf(x));
    return fmaxf(x, 0.f) + __logf(1.f + e);
}

// ---- g0 = icnn(0): row-independent constant, one thread ----
__global__ void g0_kernel(const float* __restrict__ W2, const float* __restrict__ b1,
                          const float* __restrict__ b2, const float* __restrict__ W3,
                          const float* __restrict__ b3, float* __restrict__ g0_out) {
    if (threadIdx.x != 0 || blockIdx.x != 0) return;
    float h1[H];
    for (int k = 0; k < H; ++k) h1[k] = softplusf(b1[k]);
    float z3 = b3[0];
    for (int j = 0; j < H; ++j) {
        float acc = b2[j];
        for (int k = 0; k < H; ++k) acc = fmaf(W2[j * H + k], h1[k], acc);
        z3 = fmaf(W3[j], softplusf(acc), z3);
    }
    g0_out[0] = softplusf(z3);
}

// ---- main: one row per thread; weights read via uniform (scalar) loads ----
// All weight indices depend only on compile-time constants or the uniform
// loop counter j -> the compiler emits s_load into SGPRs; inner loops are
// pure v_fma_f32 with one SGPR operand. No LDS at all.
__global__ __launch_bounds__(256) void sdnn_kernel(
    const float* __restrict__ X,   const float* __restrict__ Wf,
    const float* __restrict__ W1,  const float* __restrict__ b1,
    const float* __restrict__ W2,  const float* __restrict__ b2,
    const float* __restrict__ W3,  const float* __restrict__ b3,
    const float* __restrict__ Wim2,const float* __restrict__ Wim3,
    const float* __restrict__ g0p, float* __restrict__ out, int B)
{
    const int row = blockIdx.x * 256 + threadIdx.x;
    if (row >= B) return;

    const float2 xv = ((const float2*)X)[row];
    const float x0 = xv.x, x1 = xv.y;

    // layer 1: h1 = sp(W1 x + b1)    (W1 row-major [60,2])
    float h1v[H];
#pragma unroll
    for (int k = 0; k < H; ++k)
        h1v[k] = softplusf(fmaf(W1[2 * k], x0, fmaf(W1[2 * k + 1], x1, b1[k])));

    // G[k] accumulates sum_j W2[j][k] * t[j]   (t[j] = W3[j]*sigmoid(z2[j]))
    float G[H];
#pragma unroll
    for (int k = 0; k < H; ++k) G[k] = 0.f;

    const float wi30 = Wim3[0], wi31 = Wim3[1];
    float z3 = fmaf(wi30, x0, fmaf(wi31, x1, b3[0]));
    float gim0 = 0.f, gim1 = 0.f;   // sum_j t[j]*Wim2[j,:]

    for (int j = 0; j < H; ++j) {
        const float* __restrict__ wrow = &W2[j * H];
        // z2_j = W2[j,:]·h1 + b2_j + Wim2[j,:]·x  (4 partial accs break dep chain)
        float a0 = 0.f, a1 = 0.f, a2 = 0.f, a3 = 0.f;
#pragma unroll
        for (int k = 0; k < H; k += 4) {
            a0 = fmaf(wrow[k + 0], h1v[k + 0], a0);
            a1 = fmaf(wrow[k + 1], h1v[k + 1], a1);
            a2 = fmaf(wrow[k + 2], h1v[k + 2], a2);
            a3 = fmaf(wrow[k + 3], h1v[k + 3], a3);
        }
        float acc = ((a0 + a1) + (a2 + a3))
                  + fmaf(Wim2[2 * j], x0, fmaf(Wim2[2 * j + 1], x1, b2[j]));
        const float h2  = softplusf(acc);
        const float w3j = W3[j];
        z3 = fmaf(w3j, h2, z3);
        const float tj = w3j * (1.f - __expf(-h2));   // W3[j]*sigmoid(z2_j)
        gim0 = fmaf(tj, Wim2[2 * j],     gim0);
        gim1 = fmaf(tj, Wim2[2 * j + 1], gim1);
#pragma unroll
        for (int k = 0; k < H; ++k) G[k] = fmaf(wrow[k], tj, G[k]);
    }

    const float g0 = g0p[0];
    const float g  = softplusf(z3);
    const float s3 = 1.f - __expf(-g);        // sigmoid(z3)
    const float u3 = (g > g0) ? s3 : 0.f;     // relu'(g-g0) * sigmoid(z3)

    // q = sum_k G[k]*sigmoid(z1_k)*W1[k,:]
    float q0 = 0.f, q1 = 0.f;
#pragma unroll
    for (int k = 0; k < H; ++k) {
        const float u1 = G[k] * (1.f - __expf(-h1v[k]));
        q0 = fmaf(u1, W1[2 * k],     q0);
        q1 = fmaf(u1, W1[2 * k + 1], q1);
    }
    const float dV0 = fmaf(2.f * EPS, x0, u3 * (wi30 + gim0 + q0));
    const float dV1 = fmaf(2.f * EPS, x1, u3 * (wi31 + gim1 + q1));

    const float V  = fmaxf(g - g0, 0.f) + EPS * fmaf(x0, x0, x1 * x1);
    const float f0 = fmaf(Wf[0], x0, Wf[1] * x1);
    const float f1 = fmaf(Wf[2], x0, Wf[3] * x1);
    const float stab = fmaf(ALPHA, V, fmaf(dV0, f0, dV1 * f1));
    const float r    = fmaxf(stab, 0.f);
    const float n2   = fmaf(dV0, dV0, dV1 * dV1);
    const float s    = __fdividef(r, n2);

    float2 o;
    o.x = f0 - dV0 * s;
    o.y = f1 - dV1 * s;
    ((float2*)out)[row] = o;
}

extern "C" void kernel_launch(void* const* d_in, const int* in_sizes, int n_in,
                              void* d_out, int out_size, void* d_ws, size_t ws_size,
                              hipStream_t stream) {
    const float* X    = (const float*)d_in[0];
    const float* Wf   = (const float*)d_in[1];
    const float* W1   = (const float*)d_in[2];
    const float* b1   = (const float*)d_in[3];
    const float* W2   = (const float*)d_in[4];
    const float* b2   = (const float*)d_in[5];
    const float* W3   = (const float*)d_in[6];
    const float* b3   = (const float*)d_in[7];
    const float* Wim2 = (const float*)d_in[8];
    const float* Wim3 = (const float*)d_in[9];
    float* out   = (float*)d_out;
    float* g0buf = (float*)d_ws;

    const int B = in_sizes[0] / 2;

    hipLaunchKernelGGL(g0_kernel, dim3(1), dim3(64), 0, stream,
                       W2, b1, b2, W3, b3, g0buf);
    hipLaunchKernelGGL(sdnn_kernel, dim3((B + 255) / 256), dim3(256), 0, stream,
                       X, Wf, W1, b1, W2, b2, W3, b3, Wim2, Wim3, g0buf, out, B);
}